// Round 1
// baseline (6903.619 us; speedup 1.0000x reference)
//
#include <hip/hip_runtime.h>
#include <math.h>

#define NUMEL 6553600          // 128*32*40*40
#define NB_ELT 6400            // NUMEL/4/256
#define NCH 32
#define HWD 40
#define PLANE 1600             // 40*40

struct OdeState {
    float t, dt, h;
    int done, accept;
};

// ---------------------------------------------------------------- state
__global__ void init_state_kernel(OdeState* st) {
    st->t = 0.0f; st->dt = 0.05f; st->h = 0.0f; st->done = 0; st->accept = 0;
}

__global__ void step_init_kernel(OdeState* st) {
    if (st->done) { st->h = 0.0f; return; }
    float h = 1.0f - st->t;
    if (st->dt < h) h = st->dt;
    st->h = h;
}

// ---------------------------------------------------------------- copy
__global__ void copy4_kernel(const float4* __restrict__ in, float4* __restrict__ out) {
    int i = blockIdx.x * 256 + threadIdx.x;
    out[i] = in[i];
}

__global__ void commit_kernel(const OdeState* __restrict__ st,
                              const float4* __restrict__ y5, float4* __restrict__ y) {
    if (!st->accept) return;
    int i = blockIdx.x * 256 + threadIdx.x;
    y[i] = y5[i];
}

// ---------------------------------------------------------------- combine: u = y + h*(c0*p0 + ... )
template<int CNT>
__global__ void combine_kernel(const OdeState* __restrict__ st,
                               const float4* __restrict__ y, float4* __restrict__ u,
                               const float4* __restrict__ p0, const float4* __restrict__ p1,
                               const float4* __restrict__ p2, const float4* __restrict__ p3,
                               const float4* __restrict__ p4,
                               float c0, float c1, float c2, float c3, float c4) {
    if (st->done) return;
    const float h = st->h;
    const int i = blockIdx.x * 256 + threadIdx.x;
    float4 a = p0[i];
    float sx = c0 * a.x, sy = c0 * a.y, sz = c0 * a.z, sw = c0 * a.w;
    if (CNT > 1) { float4 b = p1[i]; sx += c1 * b.x; sy += c1 * b.y; sz += c1 * b.z; sw += c1 * b.w; }
    if (CNT > 2) { float4 b = p2[i]; sx += c2 * b.x; sy += c2 * b.y; sz += c2 * b.z; sw += c2 * b.w; }
    if (CNT > 3) { float4 b = p3[i]; sx += c3 * b.x; sy += c3 * b.y; sz += c3 * b.z; sw += c3 * b.w; }
    if (CNT > 4) { float4 b = p4[i]; sx += c4 * b.x; sy += c4 * b.y; sz += c4 * b.z; sw += c4 * b.w; }
    float4 yy = y[i];
    float4 o;
    o.x = yy.x + h * sx; o.y = yy.y + h * sy; o.z = yy.z + h * sz; o.w = yy.w + h * sw;
    u[i] = o;
}

// ---------------------------------------------------------------- conv 3x3 SAME, 32ch in/out
template<int RELU>
__launch_bounds__(320)
__global__ void conv3x3_kernel(const OdeState* __restrict__ st,
                               const float* __restrict__ in,
                               const float* __restrict__ W,
                               const float* __restrict__ bias,
                               float* __restrict__ out) {
    if (st->done) return;
    const int n    = blockIdx.y;
    const int cog  = blockIdx.x / 5;   // output-channel group of 8
    const int rowg = blockIdx.x % 5;   // row group of 8
    const int tid  = threadIdx.x;
    const int w    = tid % HWD;
    const int r0   = rowg * 8 + tid / HWD;

    const bool rm0 = (r0 > 0), rm2 = (r0 < HWD - 1);
    const bool cm0 = (w > 0),  cm2 = (w < HWD - 1);

    float acc[8];
#pragma unroll
    for (int i = 0; i < 8; ++i) acc[i] = 0.0f;

    const float* p  = in + ((size_t)n * NCH) * PLANE + r0 * HWD + w;
    const float* wq = W + (size_t)(cog * 8) * (NCH * 9);

    for (int ci = 0; ci < NCH; ++ci) {
        float v00 = (rm0 && cm0) ? p[-HWD - 1] : 0.0f;
        float v01 =  rm0         ? p[-HWD]     : 0.0f;
        float v02 = (rm0 && cm2) ? p[-HWD + 1] : 0.0f;
        float v10 =  cm0         ? p[-1]       : 0.0f;
        float v11 =               p[0];
        float v12 =  cm2         ? p[1]        : 0.0f;
        float v20 = (rm2 && cm0) ? p[HWD - 1]  : 0.0f;
        float v21 =  rm2         ? p[HWD]      : 0.0f;
        float v22 = (rm2 && cm2) ? p[HWD + 1]  : 0.0f;
        const float* wc = wq + ci * 9;
#pragma unroll
        for (int co = 0; co < 8; ++co) {
            const float* ww = wc + co * (NCH * 9);
            acc[co] = fmaf(ww[0], v00, acc[co]);
            acc[co] = fmaf(ww[1], v01, acc[co]);
            acc[co] = fmaf(ww[2], v02, acc[co]);
            acc[co] = fmaf(ww[3], v10, acc[co]);
            acc[co] = fmaf(ww[4], v11, acc[co]);
            acc[co] = fmaf(ww[5], v12, acc[co]);
            acc[co] = fmaf(ww[6], v20, acc[co]);
            acc[co] = fmaf(ww[7], v21, acc[co]);
            acc[co] = fmaf(ww[8], v22, acc[co]);
        }
        p += PLANE;
    }
    float* op = out + ((size_t)n * NCH + cog * 8) * PLANE + r0 * HWD + w;
#pragma unroll
    for (int co = 0; co < 8; ++co) {
        float r = acc[co] + bias[cog * 8 + co];
        if (RELU) r = fmaxf(r, 0.0f);
        op[co * PLANE] = r;
    }
}

// ---------------------------------------------------------------- error norm (two-pass deterministic)
__global__ void err_reduce_kernel(const OdeState* __restrict__ st, double* __restrict__ part,
                                  const float4* __restrict__ y,  const float4* __restrict__ y5,
                                  const float4* __restrict__ k1, const float4* __restrict__ k3,
                                  const float4* __restrict__ k4, const float4* __restrict__ k5,
                                  const float4* __restrict__ k6, const float4* __restrict__ k7,
                                  float e0, float e2, float e3, float e4, float e5, float e6) {
    __shared__ double red[256];
    if (st->done) return;
    const float h = st->h;
    const int i = blockIdx.x * 256 + threadIdx.x;
    float4 a = k1[i], b = k3[i], c = k4[i], d = k5[i], e = k6[i], f = k7[i];
    float4 yy = y[i], z = y5[i];
    double s = 0.0;
    {
        float er = h * (e0 * a.x + e2 * b.x + e3 * c.x + e4 * d.x + e5 * e.x + e6 * f.x);
        float tol = 1e-4f + 1e-3f * fmaxf(fabsf(yy.x), fabsf(z.x));
        float r = er / tol; s += (double)(r * r);
    }
    {
        float er = h * (e0 * a.y + e2 * b.y + e3 * c.y + e4 * d.y + e5 * e.y + e6 * f.y);
        float tol = 1e-4f + 1e-3f * fmaxf(fabsf(yy.y), fabsf(z.y));
        float r = er / tol; s += (double)(r * r);
    }
    {
        float er = h * (e0 * a.z + e2 * b.z + e3 * c.z + e4 * d.z + e5 * e.z + e6 * f.z);
        float tol = 1e-4f + 1e-3f * fmaxf(fabsf(yy.z), fabsf(z.z));
        float r = er / tol; s += (double)(r * r);
    }
    {
        float er = h * (e0 * a.w + e2 * b.w + e3 * c.w + e4 * d.w + e5 * e.w + e6 * f.w);
        float tol = 1e-4f + 1e-3f * fmaxf(fabsf(yy.w), fabsf(z.w));
        float r = er / tol; s += (double)(r * r);
    }
    red[threadIdx.x] = s;
    __syncthreads();
    for (int k = 128; k > 0; k >>= 1) {
        if (threadIdx.x < k) red[threadIdx.x] += red[threadIdx.x + k];
        __syncthreads();
    }
    if (threadIdx.x == 0) part[blockIdx.x] = red[0];
}

__global__ void finish_kernel(OdeState* st, const double* __restrict__ part) {
    __shared__ double red[256];
    if (st->done) { if (threadIdx.x == 0) st->accept = 0; return; }
    double s = 0.0;
    for (int i = threadIdx.x; i < NB_ELT; i += 256) s += part[i];
    red[threadIdx.x] = s;
    __syncthreads();
    for (int k = 128; k > 0; k >>= 1) {
        if (threadIdx.x < k) red[threadIdx.x] += red[threadIdx.x + k];
        __syncthreads();
    }
    if (threadIdx.x == 0) {
        float en = (float)sqrt(red[0] / (double)NUMEL);
        int accept = (en <= 1.0f) ? 1 : 0;
        float t = st->t;
        if (accept) t = t + st->h;
        float factor = 0.9f * powf(en + 1e-10f, -0.2f);
        factor = fminf(fmaxf(factor, 0.2f), 10.0f);
        st->dt = st->dt * factor;
        st->t = t;
        st->accept = accept;
        st->done = (t >= 1.0f - 1e-6f) ? 1 : 0;
    }
}

// ---------------------------------------------------------------- launch
extern "C" void kernel_launch(void* const* d_in, const int* in_sizes, int n_in,
                              void* d_out, int out_size, void* d_ws, size_t ws_size,
                              hipStream_t stream) {
    const float* x  = (const float*)d_in[0];
    const float* W1 = (const float*)d_in[1];
    const float* b1 = (const float*)d_in[2];
    const float* W2 = (const float*)d_in[3];
    const float* b2 = (const float*)d_in[4];
    float* y = (float*)d_out;

    // workspace layout: 8 slabs of NUMEL floats, then state, then partials
    const size_t slab = (size_t)NUMEL;
    float* u   = (float*)d_ws;           // also k7
    float* tmp = u + slab;
    float* k1  = u + 2 * slab;
    float* k2  = u + 3 * slab;           // also y5
    float* k3  = u + 4 * slab;
    float* k4  = u + 5 * slab;
    float* k5  = u + 6 * slab;
    float* k6  = u + 7 * slab;
    float* k7  = u;                      // alias
    float* y5  = k2;                     // alias
    char* base = (char*)d_ws + 8 * slab * sizeof(float);
    OdeState* st = (OdeState*)base;
    double* part = (double*)(base + 256);
    size_t needed = 8 * slab * sizeof(float) + 256 + (size_t)NB_ELT * sizeof(double);
    if (ws_size < needed) return;  // workspace too small -> fail visibly

    // dopri5 tableau in fp32, matching numpy's rounding
    const float A21 = 0.2f;
    const float A31 = (float)(3.0 / 40.0),      A32 = (float)(9.0 / 40.0);
    const float A41 = (float)(44.0 / 45.0),     A42 = (float)(-56.0 / 15.0),   A43 = (float)(32.0 / 9.0);
    const float A51 = (float)(19372.0 / 6561.0),A52 = (float)(-25360.0 / 2187.0),
                A53 = (float)(64448.0 / 6561.0),A54 = (float)(-212.0 / 729.0);
    const float A61 = (float)(9017.0 / 3168.0), A62 = (float)(-355.0 / 33.0),
                A63 = (float)(46732.0 / 5247.0),A64 = (float)(49.0 / 176.0),
                A65 = (float)(-5103.0 / 18656.0);
    const float B50 = (float)(35.0 / 384.0),    B52 = (float)(500.0 / 1113.0),
                B53 = (float)(125.0 / 192.0),   B54 = (float)(-2187.0 / 6784.0),
                B55 = (float)(11.0 / 84.0);
    const float B40 = (float)(5179.0 / 57600.0),B42 = (float)(7571.0 / 16695.0),
                B43 = (float)(393.0 / 640.0),   B44 = (float)(-92097.0 / 339200.0),
                B45 = (float)(187.0 / 2100.0),  B46 = (float)(1.0 / 40.0);
    const float E0 = B50 - B40, E2 = B52 - B42, E3 = B53 - B43,
                E4 = B54 - B44, E5 = B55 - B45, E6 = -B46;

    const dim3 cgrid(20, 128, 1);
    const int CBLK = 320;
    const float4* nul = nullptr;

    init_state_kernel<<<1, 1, 0, stream>>>(st);
    copy4_kernel<<<NB_ELT, 256, 0, stream>>>((const float4*)x, (float4*)y);

#define CONV1(src, dst) conv3x3_kernel<1><<<cgrid, CBLK, 0, stream>>>(st, src, W1, b1, dst)
#define CONV2(src, dst) conv3x3_kernel<0><<<cgrid, CBLK, 0, stream>>>(st, src, W2, b2, dst)
#define F4(p) ((const float4*)(p))

    for (int step = 0; step < 32; ++step) {
        step_init_kernel<<<1, 1, 0, stream>>>(st);
        // k1 = f(y)
        CONV1(y, tmp); CONV2(tmp, k1);
        // k2
        combine_kernel<1><<<NB_ELT, 256, 0, stream>>>(st, F4(y), (float4*)u,
            F4(k1), nul, nul, nul, nul, A21, 0, 0, 0, 0);
        CONV1(u, tmp); CONV2(tmp, k2);
        // k3
        combine_kernel<2><<<NB_ELT, 256, 0, stream>>>(st, F4(y), (float4*)u,
            F4(k1), F4(k2), nul, nul, nul, A31, A32, 0, 0, 0);
        CONV1(u, tmp); CONV2(tmp, k3);
        // k4
        combine_kernel<3><<<NB_ELT, 256, 0, stream>>>(st, F4(y), (float4*)u,
            F4(k1), F4(k2), F4(k3), nul, nul, A41, A42, A43, 0, 0);
        CONV1(u, tmp); CONV2(tmp, k4);
        // k5
        combine_kernel<4><<<NB_ELT, 256, 0, stream>>>(st, F4(y), (float4*)u,
            F4(k1), F4(k2), F4(k3), F4(k4), nul, A51, A52, A53, A54, 0);
        CONV1(u, tmp); CONV2(tmp, k5);
        // k6
        combine_kernel<5><<<NB_ELT, 256, 0, stream>>>(st, F4(y), (float4*)u,
            F4(k1), F4(k2), F4(k3), F4(k4), F4(k5), A61, A62, A63, A64, A65);
        CONV1(u, tmp); CONV2(tmp, k6);
        // y5 (reuses k2 slab; k2 is dead now)
        combine_kernel<5><<<NB_ELT, 256, 0, stream>>>(st, F4(y), (float4*)y5,
            F4(k1), F4(k3), F4(k4), F4(k5), F4(k6), B50, B52, B53, B54, B55);
        // k7 = f(y5) (reuses u slab)
        CONV1(y5, tmp); CONV2(tmp, k7);
        // error norm
        err_reduce_kernel<<<NB_ELT, 256, 0, stream>>>(st, part,
            F4(y), F4(y5), F4(k1), F4(k3), F4(k4), F4(k5), F4(k6), F4(k7),
            E0, E2, E3, E4, E5, E6);
        finish_kernel<<<1, 256, 0, stream>>>(st, part);
        // y = accept ? y5 : y
        commit_kernel<<<NB_ELT, 256, 0, stream>>>(st, F4(y5), (float4*)y);
    }
#undef CONV1
#undef CONV2
#undef F4
}